// Round 8
// baseline (510.898 us; speedup 1.0000x reference)
//
#include <hip/hip_runtime.h>
#include <hip/hip_fp8.h>
#include <cstdint>

#define NROWS_HALF 32768
#define NPTS 1000
#define QC_OFF 4194304            // quantized_coord offset in d_out (floats)
#define LOSS_OFF 8388608          // loss offset in d_out (floats)

// ws layout (bytes):
//   [0, 133120)        Vh bf16 [1040][64]: rows 0..999 coord vecs (RN hi),
//                      1000..1007 zero, 1008..1039 = M codes
//   [133120, 266240)   Vl bf16 [1040][64]: RN lo residuals
//   [266240, 331776)   V8T fp8 e4m3 [64][1024] d-major coord vecs (cols>=1000 zero)
//   [331776]           fp32 loss accumulator
#define U_VH 0                    // ushort index
#define U_VL 66560                // ushort index
#define WS_V8T_BYTE 266240
#define WS_LOSS_BYTE 331776

#define X_STRIDE 68
#define WROWB 1032                // byte stride of W_s rows (1024 + 8 pad)

typedef short short8 __attribute__((ext_vector_type(8)));
typedef float float4v __attribute__((ext_vector_type(4)));

#define MFMA16(a, b, c) __builtin_amdgcn_mfma_f32_16x16x32_bf16((a), (b), (c), 0, 0, 0)

// ---------------- Threefry-2x32 (20 rounds), matches JAX ----------------
__host__ __device__ __forceinline__ void tf2x32(uint32_t k0, uint32_t k1,
                                                uint32_t x0, uint32_t x1,
                                                uint32_t& o0, uint32_t& o1) {
  const uint32_t k2 = k0 ^ k1 ^ 0x1BD11BDAu;
#define TF_R(r) { x0 += x1; x1 = (x1 << (r)) | (x1 >> (32 - (r))); x1 ^= x0; }
  x0 += k0; x1 += k1;
  TF_R(13) TF_R(15) TF_R(26) TF_R(6)
  x0 += k1; x1 += k2 + 1u;
  TF_R(17) TF_R(29) TF_R(16) TF_R(24)
  x0 += k2; x1 += k0 + 2u;
  TF_R(13) TF_R(15) TF_R(26) TF_R(6)
  x0 += k0; x1 += k1 + 3u;
  TF_R(17) TF_R(29) TF_R(16) TF_R(24)
  x0 += k1; x1 += k2 + 4u;
  TF_R(13) TF_R(15) TF_R(26) TF_R(6)
  x0 += k2; x1 += k0 + 5u;
#undef TF_R
  o0 = x0; o1 = x1;
}

// l = -log(u + 1e-20) + 1e-20  (positive), u = (bits>>9 | 1.0f) - 1.0f.
// weight uses exp(g/2) = rsqrt(l). Near u->1: exact-delta series.
__device__ __forceinline__ float neglog_u(uint32_t bits) {
  const uint32_t mant = bits >> 9;
  const float u = __uint_as_float(mant | 0x3f800000u) - 1.0f;
  const float delta = (float)(8388608u - mant) * 1.1920928955078125e-7f;
  float l;
  if (delta < 0.00390625f) {
    l = delta + 0.5f * delta * delta + 0.33333333f * delta * delta * delta;
  } else {
    l = -__logf(u + 1e-20f);
  }
  return l + 1e-20f;
}

// full gumbel (used only in the tiny codebook path)
__device__ __forceinline__ float gumbel_from_bits(uint32_t bits) {
  return -__logf(neglog_u(bits));
}

// round-to-nearest-even bf16 (returns 16-bit pattern in low bits)
__device__ __forceinline__ uint32_t rn16(float f) {
  uint32_t u = __float_as_uint(f);
  return (u + 0x7FFFu + ((u >> 16) & 1u)) >> 16;
}

__device__ __forceinline__ void split2_rn(float f0, float f1, uint32_t& hi, uint32_t& lo) {
  uint32_t h0 = rn16(f0), h1 = rn16(f1);
  hi = h0 | (h1 << 16);
  float l0 = f0 - __uint_as_float(h0 << 16);
  float l1 = f1 - __uint_as_float(h1 << 16);
  lo = rn16(l0) | (rn16(l1) << 16);
}

__device__ __forceinline__ void split8_rn(const float* p, short8& hi, short8& lo) {
  float4 f0 = *(const float4*)p;
  float4 f1 = *(const float4*)(p + 4);
  union { uint32_t u[4]; short8 s; } H, L;
  split2_rn(f0.x, f0.y, H.u[0], L.u[0]);
  split2_rn(f0.z, f0.w, H.u[1], L.u[1]);
  split2_rn(f1.x, f1.y, H.u[2], L.u[2]);
  split2_rn(f1.z, f1.w, H.u[3], L.u[3]);
  hi = H.s; lo = L.s;
}

__device__ __forceinline__ short8 as_s8(uint4 v) {
  union { uint4 u; short8 s; } c; c.u = v; return c.s;
}

// fp8 e4m3 pack of two floats -> 2 bytes (low = f0)
__device__ __forceinline__ ushort pk_fp8(float f0, float f1) {
#if __has_builtin(__builtin_amdgcn_cvt_pk_fp8_f32)
  return (ushort)(__builtin_amdgcn_cvt_pk_fp8_f32(f0, f1, 0, false) & 0xffff);
#else
  __hip_fp8_e4m3 a(f0), b(f1);
  return (ushort)a.__x | ((ushort)b.__x << 8);
#endif
}

__device__ __forceinline__ float grid_vec(int n, int c, const float* __restrict__ lw,
                                          const float* __restrict__ lb) {
  int jx = (n / 10) % 10, iy = n / 100, kz = n % 10;
  const double step = 1.5 / 9.0;
  float gx = (float)(jx * step), gy = (float)(iy * step), gz = (float)(kz * step);
  return gx * lw[c * 3 + 0] + gy * lw[c * 3 + 1] + gz * lw[c * 3 + 2] + lb[c];
}

// one 16-col tile of GEMM1: 3-MFMA split-bf16 (hi+lo), B rows nb..nb+15
__device__ __forceinline__ float4v tile_mfma(const ushort* __restrict__ Vh,
                                             const ushort* __restrict__ Vl,
                                             int nb, const short8* ah, const short8* al) {
  uint4 bh0 = *(const uint4*)(Vh + nb);
  uint4 bl0 = *(const uint4*)(Vl + nb);
  uint4 bh1 = *(const uint4*)(Vh + nb + 32);
  uint4 bl1 = *(const uint4*)(Vl + nb + 32);
  float4v acc = {0.f, 0.f, 0.f, 0.f};
  acc = MFMA16(ah[0], as_s8(bh0), acc);
  acc = MFMA16(ah[0], as_s8(bl0), acc);
  acc = MFMA16(al[0], as_s8(bh0), acc);
  acc = MFMA16(ah[1], as_s8(bh1), acc);
  acc = MFMA16(ah[1], as_s8(bl1), acc);
  acc = MFMA16(al[1], as_s8(bh1), acc);
  return acc;
}

// ---------------- setup: V tables (bf16 + fp8) + M codes + loss=0 ----------------
__global__ void setup_kernel(const float* __restrict__ lw, const float* __restrict__ lb,
                             const float* __restrict__ emb, const float* __restrict__ lws,
                             ushort* __restrict__ wsu) {
  int idx = blockIdx.x * 256 + threadIdx.x;
  if (idx < 66560) {
    int n = idx >> 6, c = idx & 63;
    float v;
    if (n < NPTS) {
      v = grid_vec(n, c, lw, lb);
    } else if (n < 1008) {
      v = 0.f;
    } else {
      int m = n - 1008, k = m >> 3;
      float a = 0.f;
      #pragma unroll
      for (int e = 0; e < 16; ++e) a += emb[m * 16 + e] * lws[(k * 16 + e) * 64 + c];
      v = a;
    }
    uint32_t h = rn16(v);
    float fl = v - __uint_as_float(h << 16);
    wsu[U_VH + idx] = (ushort)h;
    wsu[U_VL + idx] = (ushort)rn16(fl);
  } else if (idx < 82944) {
    int i2 = idx - 66560;              // d*256 + n4: 4 fp8 values each
    int d = i2 >> 8, n4 = (i2 & 255) << 2;
    float v0 = (n4 + 0 < NPTS) ? grid_vec(n4 + 0, d, lw, lb) : 0.f;
    float v1 = (n4 + 1 < NPTS) ? grid_vec(n4 + 1, d, lw, lb) : 0.f;
    float v2 = (n4 + 2 < NPTS) ? grid_vec(n4 + 2, d, lw, lb) : 0.f;
    float v3 = (n4 + 3 < NPTS) ? grid_vec(n4 + 3, d, lw, lb) : 0.f;
    uint32_t p = (uint32_t)pk_fp8(v0, v1) | ((uint32_t)pk_fp8(v2, v3) << 16);
    *(uint32_t*)((char*)wsu + WS_V8T_BYTE + d * 1024 + n4) = p;
  } else if (idx == 82944) {
    *(float*)((char*)wsu + WS_LOSS_BYTE) = 0.f;
  }
}

// ---------------- fused main kernel: 4096 blocks x 256 ----------------
// Block: 16 local rows; lr 0..7 -> g0+lr, lr 8..15 -> g0+lr-8+32768 (threefry pairs)
__global__ __launch_bounds__(256, 6) void fused_kernel(
    const float* __restrict__ inp, const float* __restrict__ emb,
    const float* __restrict__ lw, const float* __restrict__ lb,
    const ushort* __restrict__ wsu, float* __restrict__ out,
    float* __restrict__ loss_acc,
    uint32_t kc0, uint32_t kc1, uint32_t kp0, uint32_t kp1) {

  __shared__ float x_s[16 * X_STRIDE];    // input rows; later q output
  __shared__ long  W_l[16 * WROWB / 8];   // fp8 gumbel weights [16][1032] bytes
  __shared__ float xp_s[16 * 32];         // codebook logits
  __shared__ float red_s[192];            // [0,64) s0, [64,128) s1, [128,192) sw
  __shared__ float max_s[16];             // exact per-row logit max
  __shared__ float kl_s;

  uchar* W8 = (uchar*)W_l;
  const int t = threadIdx.x;
  const int lane = t & 63;
  const int w = t >> 6;
  const int q = lane >> 4;
  const int mn = lane & 15;
  const int g0 = blockIdx.x * 8;

  if (t == 0) kl_s = 0.f;

  // per-lane projection coefficients (lane = channel c)
  const float pw0 = lw[lane * 3 + 0];
  const float pw1 = lw[lane * 3 + 1];
  const float pw2 = lw[lane * 3 + 2];
  const float pbb = lb[lane];

  // ---- load 16 input rows + EXACT per-row logit max ----
  // max over grid = 1.5*(relu(u0)+relu(u1)+relu(u2)) + beta; u = W^T x, beta = x.b
  #pragma unroll
  for (int it = 0; it < 4; ++it) {
    int rl = it * 4 + w;
    int row = (rl < 8) ? (g0 + rl) : (g0 + rl - 8 + NROWS_HALF);
    float v = inp[row * 64 + lane];
    x_s[rl * X_STRIDE + lane] = v;
    float u0 = v * pw0, u1 = v * pw1, u2 = v * pw2, u3 = v * pbb;
    #pragma unroll
    for (int off = 32; off > 0; off >>= 1) {
      u0 += __shfl_xor(u0, off);
      u1 += __shfl_xor(u1, off);
      u2 += __shfl_xor(u2, off);
      u3 += __shfl_xor(u3, off);
    }
    if (lane == 0)
      max_s[rl] = 1.5f * (fmaxf(u0, 0.f) + fmaxf(u1, 0.f) + fmaxf(u2, 0.f)) + u3;
  }
  __syncthreads();

  // ---- A fragments (rows = local rows, m = mn) ----
  short8 ah[2], al[2];
  #pragma unroll
  for (int s = 0; s < 2; ++s)
    split8_rn(&x_s[mn * X_STRIDE + s * 32 + q * 8], ah[s], al[s]);

  float mrow[4];
  #pragma unroll
  for (int r = 0; r < 4; ++r) mrow[r] = max_s[q * 4 + r];

  const ushort* Vh = wsu + U_VH;
  const ushort* Vl = wsu + U_VL;
  const int rbase = (q & 1) * 4;
  const bool low = (q < 2);

  float s0[4] = {0.f, 0.f, 0.f, 0.f};
  float s1[4] = {0.f, 0.f, 0.f, 0.f};
  float sw[4] = {0.f, 0.f, 0.f, 0.f};

  // ---- streaming GEMM1 + KL stats + gumbel weights, tile-pairs (i, i+8) ----
  #pragma unroll 2
  for (int i = 0; i < 8; ++i) {
    const int jA = w + 4 * i, jB = jA + 32;
    float4v accA = tile_mfma(Vh, Vl, (jA * 16 + mn) * 64 + q * 8, ah, al);
    float4v accB;
    if (jB < 63) {
      accB = tile_mfma(Vh, Vl, (jB * 16 + mn) * 64 + q * 8, ah, al);
      if (jB == 62 && mn >= 8) accB = (float4v){-1e30f, -1e30f, -1e30f, -1e30f};
    } else {
      accB = (float4v){-1e30f, -1e30f, -1e30f, -1e30f};
    }
    const int colA = jA * 16 + mn, colB = jB * 16 + mn;
    #pragma unroll
    for (int r = 0; r < 4; ++r) {
      // ew = exp((logit-m)/2): KL uses ew^2, weight uses ew*rsqrt(l)
      float ewA = __expf((accA[r] - mrow[r]) * 0.5f);
      float ewB = __expf((accB[r] - mrow[r]) * 0.5f);
      float e2A = ewA * ewA, e2B = ewB * ewB;
      s0[r] += e2A + e2B;
      s1[r] += e2A * accA[r] + e2B * accB[r];
      // threefry noise (paired via shfl_xor 32)
      const uint32_t rowAg = (uint32_t)(g0 + rbase + r);
      const uint32_t nown = low ? (uint32_t)colA : (uint32_t)colB;
      uint32_t y0, y1;
      uint32_t j0 = rowAg * 1000u + nown;
      tf2x32(kc0, kc1, j0, j0 + 32768000u, y0, y1);
      uint32_t send = low ? y1 : y0;
      uint32_t recv = (uint32_t)__shfl_xor((int)send, 32);
      uint32_t bA = low ? y0 : recv;
      uint32_t bB = low ? recv : y1;
      const int myrow = q * 4 + r;
      float wA = fminf(ewA * rsqrtf(neglog_u(bA)), 448.f);
      float wB = fminf(ewB * rsqrtf(neglog_u(bB)), 448.f);
      sw[r] += wA + wB;
      // pack fp8 pairs via neighbor shuffle; even lane stores 2 bytes
      float wAn = __shfl_xor(wA, 1);
      float wBn = __shfl_xor(wB, 1);
      if (!(lane & 1)) {
        *(ushort*)(W8 + myrow * WROWB + (colA ^ (r * 8))) = pk_fp8(wA, wAn);
        if (colB < 1008)
          *(ushort*)(W8 + myrow * WROWB + (colB ^ (r * 8))) = pk_fp8(wB, wBn);
      }
    }
  }

  // ---- reduce stats over mn within quad; stash wave-partials ----
  #pragma unroll
  for (int off = 1; off < 16; off <<= 1) {
    #pragma unroll
    for (int r = 0; r < 4; ++r) {
      s0[r] += __shfl_xor(s0[r], off);
      s1[r] += __shfl_xor(s1[r], off);
      sw[r] += __shfl_xor(sw[r], off);
    }
  }
  if (mn == 0) {
    #pragma unroll
    for (int r = 0; r < 4; ++r) {
      red_s[w * 16 + q * 4 + r] = s0[r];
      red_s[64 + w * 16 + q * 4 + r] = s1[r];
      red_s[128 + w * 16 + q * 4 + r] = sw[r];
    }
  }

  // ---- code tiles: xp logits via same A-frags (M rows 1008..1039) ----
  if (w == 0 || w == 3) {
    const int ct = (w == 0) ? 64 : 63;
    float4v acc = tile_mfma(Vh, Vl, (ct * 16 + mn) * 64 + q * 8, ah, al);
    #pragma unroll
    for (int r = 0; r < 4; ++r)
      xp_s[(q * 4 + r) * 32 + (ct - 63) * 16 + mn] = acc[r];
  }

  // ---- zero LOGICAL pad cols 1008..1023 through the per-row XOR map ----
  {
    int rowp = t >> 4;
    int cp = 1008 + (t & 15);
    W8[rowp * WROWB + (cp ^ ((rowp & 3) * 8))] = 0;
  }
  __syncthreads();

  // ---- KL finalize (t<16) ----
  if (t < 16) {
    float S0 = (red_s[t] + red_s[16 + t]) + (red_s[32 + t] + red_s[48 + t]);
    float S1 = (red_s[64 + t] + red_s[80 + t]) + (red_s[96 + t] + red_s[112 + t]);
    atomicAdd(&kl_s, S1 / S0 - (max_s[t] + __logf(S0)) + 6.9077552790f);
  }

  // ---- GEMM2 (fp8 MFMA): qc[16][64] = W[16][1024] . V; wave w -> d-tile w ----
  {
    const uchar* V8 = (const uchar*)wsu + WS_V8T_BYTE;
    const int dq = w * 16 + mn;
    const int swz = (mn & 3) * 8;
    float4v acc = {0.f, 0.f, 0.f, 0.f};
    #pragma unroll 4
    for (int s = 0; s < 32; ++s) {
      long aw = *(const long*)(W8 + mn * WROWB + ((s * 32 + q * 8) ^ swz));
      long bv = *(const long*)(V8 + dq * 1024 + s * 32 + q * 8);
      acc = __builtin_amdgcn_mfma_f32_16x16x32_fp8_fp8(aw, bv, acc, 0, 0, 0);
    }
    #pragma unroll
    for (int r = 0; r < 4; ++r) {
      int m = q * 4 + r;
      float sww = (red_s[128 + m] + red_s[144 + m]) + (red_s[160 + m] + red_s[176 + m]);
      int grow = (m < 8) ? (g0 + m) : (g0 + m - 8 + NROWS_HALF);
      out[QC_OFF + grow * 64 + dq] = acc[r] / sww;
    }
  }

  // ---- 5b: per (pair p, k) codebook path; 8 lanes per wave (32 units) ----
  float* q_s = x_s;   // x dead (A-frags extracted pre-loop)
  if (lane < 8) {
    const int u = w * 8 + lane;
    const int p = u >> 2, k = u & 3;
    const int rA = p, rB = p + 8;
    float xpA[8], xpB[8];
    #pragma unroll
    for (int n = 0; n < 8; ++n) {
      xpA[n] = xp_s[rA * 32 + k * 8 + n];
      xpB[n] = xp_s[rB * 32 + k * 8 + n];
    }
    float mA = xpA[0], mB = xpB[0];
    #pragma unroll
    for (int n = 1; n < 8; ++n) { mA = fmaxf(mA, xpA[n]); mB = fmaxf(mB, xpB[n]); }
    float s0A = 0.f, s1A = 0.f, s0B = 0.f, s1B = 0.f;
    #pragma unroll
    for (int n = 0; n < 8; ++n) {
      float eA = __expf(xpA[n] - mA); s0A += eA; s1A += eA * xpA[n];
      float eB = __expf(xpB[n] - mB); s0B += eB; s1B += eB * xpB[n];
    }
    atomicAdd(&kl_s, (s1A / s0A - (mA + __logf(s0A)) + 2.0794415417f) +
                     (s1B / s0B - (mB + __logf(s0B)) + 2.0794415417f));
    uint32_t base = (uint32_t)(g0 + p) * 32u + (uint32_t)k * 8u;
    float tA[8], tB[8], m2A = -3.0e38f, m2B = -3.0e38f;
    #pragma unroll
    for (int n = 0; n < 8; ++n) {
      uint32_t y0, y1;
      tf2x32(kp0, kp1, base + n, base + n + 1048576u, y0, y1);
      tA[n] = (xpA[n] + gumbel_from_bits(y0)) * 0.5f;
      tB[n] = (xpB[n] + gumbel_from_bits(y1)) * 0.5f;
      m2A = fmaxf(m2A, tA[n]); m2B = fmaxf(m2B, tB[n]);
    }
    float wvA[8], wvB[8], swA = 0.f, swB = 0.f;
    #pragma unroll
    for (int n = 0; n < 8; ++n) {
      wvA[n] = __expf(tA[n] - m2A); swA += wvA[n];
      wvB[n] = __expf(tB[n] - m2B); swB += wvB[n];
    }
    float invA = 1.0f / swA, invB = 1.0f / swB;
    #pragma unroll
    for (int e = 0; e < 16; ++e) {
      float aA = 0.f, aB = 0.f;
      #pragma unroll
      for (int n = 0; n < 8; ++n) {
        float ev = emb[(k * 8 + n) * 16 + e];
        aA += wvA[n] * ev; aB += wvB[n] * ev;
      }
      q_s[rA * X_STRIDE + k * 16 + e] = aA * invA;
      q_s[rB * X_STRIDE + k * 16 + e] = aB * invB;
    }
  }
  __syncthreads();

  // ---- copyout quantized (coalesced) + loss partial ----
  #pragma unroll
  for (int it = 0; it < 4; ++it) {
    int idx = it * 256 + t;
    int rl = idx >> 6, c = idx & 63;
    int row = (rl < 8) ? (g0 + rl) : (g0 + rl - 8 + NROWS_HALF);
    out[row * 64 + c] = q_s[rl * X_STRIDE + c];
  }
  if (t == 0) atomicAdd(loss_acc, kl_s);
}

__global__ void finalize_kernel(const float* __restrict__ loss_acc, float* __restrict__ out) {
  if (threadIdx.x == 0 && blockIdx.x == 0) out[LOSS_OFF] = loss_acc[0] * 0.2f;
}

extern "C" void kernel_launch(void* const* d_in, const int* in_sizes, int n_in,
                              void* d_out, int out_size, void* d_ws, size_t ws_size,
                              hipStream_t stream) {
  const float* inp  = (const float*)d_in[0];   // [32,2048,64]
  const float* lw   = (const float*)d_in[1];   // [64,3]
  const float* lb   = (const float*)d_in[2];   // [64]
  const float* emb  = (const float*)d_in[3];   // [32,16] normalized
  const float* lws  = (const float*)d_in[4];   // [4,16,64]
  float* out = (float*)d_out;
  ushort* wsu = (ushort*)d_ws;
  float* loss = (float*)((char*)d_ws + WS_LOSS_BYTE);

  // JAX PRNG keys: key(42) -> [0,42]; split = threefry over iota(4)
  uint32_t a0, b0, a1, b1;
  tf2x32(0u, 42u, 0u, 2u, a0, b0);
  tf2x32(0u, 42u, 1u, 3u, a1, b1);
  const uint32_t kc0 = a0, kc1 = a1;   // coord-noise key
  const uint32_t kp0 = b0, kp1 = b1;   // codebook-noise key

  setup_kernel<<<325, 256, 0, stream>>>(lw, lb, emb, lws, wsu);
  fused_kernel<<<4096, 256, 0, stream>>>(inp, emb, lw, lb, wsu, out, loss,
                                         kc0, kc1, kp0, kp1);
  finalize_kernel<<<1, 64, 0, stream>>>(loss, out);
}